// Round 4
// baseline (2744.322 us; speedup 1.0000x reference)
//
#include <hip/hip_runtime.h>
#include <hip/hip_bf16.h>

// Problem constants
#define DIM    16
#define BATCH  32
#define KL     4          // Lindblad operators
#define NTS    512        // Euler steps
#define NC     4          // control channels
#define NPAR   16         // spline params per channel
#define SS     20         // LDS row stride in floats
#define DTF    (1.0f/512.0f)

__device__ __forceinline__ float b2f(__hip_bfloat16 x) { return __bfloat162float(x); }

// dtype-agnostic scalar load: inputs may be stored f32 or bf16 (detected at runtime)
__device__ __forceinline__ float ldval(const void* p, int idx, bool isf32) {
  return isf32 ? ((const float*)p)[idx]
               : __bfloat162float(((const __hip_bfloat16*)p)[idx]);
}

__global__ __launch_bounds__(256)
void lindblad_evolve(const void* __restrict__ g_params,
                     const void* __restrict__ g_H0re, const void* __restrict__ g_H0im,
                     const void* __restrict__ g_Hcre, const void* __restrict__ g_Hcim,
                     const void* __restrict__ g_Lre,  const void* __restrict__ g_Lim,
                     const void* __restrict__ g_r0re, const void* __restrict__ g_r0im,
                     float* __restrict__ g_out)      // <-- reference output dtype is float32
{
  __shared__ float sU[NTS][NC];                      // control pulses
  __shared__ float sH0r[DIM*SS], sH0i[DIM*SS];       // herm(H0)
  __shared__ float sHcr[NC][DIM*SS], sHci[NC][DIM*SS]; // herm(Hc)
  __shared__ float sDr[DIM*SS],  sDi[DIM*SS];        // LdL = sum_k L_k^dag L_k
  __shared__ float sLr[KL][DIM*SS], sLi[KL][DIM*SS]; // L_k
  __shared__ float sHr[DIM*SS],  sHi[DIM*SS];        // H(t)
  __shared__ float sRr[DIM*SS],  sRi[DIM*SS];        // rho(t)
  __shared__ float sTr[KL][DIM*SS], sTi[KL][DIM*SS]; // T_k = L_k rho
  __shared__ int sFlag;

  const int tid = threadIdx.x;
  const int b   = blockIdx.x;
  const int i   = tid >> 4;
  const int j   = tid & 15;

  // ---- input storage-dtype detection (f32 storage misread as bf16 -> huge values) ----
  if (tid == 0) sFlag = 0;
  __syncthreads();
  {
    float v = b2f(((const __hip_bfloat16*)g_H0re)[tid]);
    if (!(fabsf(v) <= 1e10f)) atomicOr(&sFlag, 1);   // also catches NaN
  }
  __syncthreads();
  const bool isf32 = (sFlag != 0);

  // ---- B-spline control pulses u[t][c] (Cox-de Boor, clamped knots) ----
  {
    float kn[20];
    kn[0] = 0.f; kn[1] = 0.f; kn[2] = 0.f;
    #pragma unroll
    for (int q = 0; q < 14; ++q) kn[3 + q] = (float)q / 13.0f;
    kn[17] = 1.f; kn[18] = 1.f; kn[19] = 1.f;
    #pragma unroll
    for (int rep = 0; rep < 2; ++rep) {
      const int ts = tid + rep * 256;
      const float t = (float)ts * DTF;
      float B[19];
      #pragma unroll
      for (int q = 0; q < 19; ++q) B[q] = (kn[q] <= t && t < kn[q+1]) ? 1.f : 0.f;
      #pragma unroll
      for (int d = 1; d <= 3; ++d) {
        #pragma unroll
        for (int q = 0; q + d < 19; ++q) {
          float ld = kn[q+d]   - kn[q];
          float rd = kn[q+d+1] - kn[q+1];
          float lv = (ld > 0.f) ? (t - kn[q])     / ld * B[q]   : 0.f;
          float rv = (rd > 0.f) ? (kn[q+d+1] - t) / rd * B[q+1] : 0.f;
          B[q] = lv + rv;   // ascending in-place: reads old B[q], old B[q+1]
        }
      }
      #pragma unroll
      for (int c = 0; c < NC; ++c) {
        float s = 0.f;
        #pragma unroll
        for (int q = 0; q < NPAR; ++q) s += B[q] * ldval(g_params, q*NC + c, isf32);
        sU[ts][c] = s;
      }
    }
  }

  // ---- constants ----
  {
    const int ij = i*16 + j, ji = j*16 + i;
    sH0r[i*SS + j] = 0.5f * (ldval(g_H0re, ij, isf32) + ldval(g_H0re, ji, isf32));
    sH0i[i*SS + j] = 0.5f * (ldval(g_H0im, ij, isf32) - ldval(g_H0im, ji, isf32));
    #pragma unroll
    for (int c = 0; c < NC; ++c) {
      sHcr[c][i*SS + j] = 0.5f * (ldval(g_Hcre, c*256 + ij, isf32) + ldval(g_Hcre, c*256 + ji, isf32));
      sHci[c][i*SS + j] = 0.5f * (ldval(g_Hcim, c*256 + ij, isf32) - ldval(g_Hcim, c*256 + ji, isf32));
    }
    // LdL[i][j] = sum_{k,m} conj(L[k][m][i]) * L[k][m][j]
    float ldr = 0.f, ldi = 0.f;
    for (int k = 0; k < KL; ++k) {
      #pragma unroll
      for (int m = 0; m < DIM; ++m) {
        float ar = ldval(g_Lre, k*256 + m*16 + i, isf32), ai = ldval(g_Lim, k*256 + m*16 + i, isf32);
        float br = ldval(g_Lre, k*256 + m*16 + j, isf32), bi = ldval(g_Lim, k*256 + m*16 + j, isf32);
        ldr += ar*br + ai*bi;   // conj(a)*b
        ldi += ar*bi - ai*br;
      }
    }
    sDr[i*SS + j] = ldr;
    sDi[i*SS + j] = ldi;
    #pragma unroll
    for (int k = 0; k < KL; ++k) {
      sLr[k][i*SS + j] = ldval(g_Lre, k*256 + i*16 + j, isf32);
      sLi[k][i*SS + j] = ldval(g_Lim, k*256 + i*16 + j, isf32);
    }
  }
  float rr = ldval(g_r0re, b*256 + i*16 + j, isf32);   // own rho element
  float ri = ldval(g_r0im, b*256 + i*16 + j, isf32);
  sRr[i*SS + j] = rr;
  sRi[i*SS + j] = ri;

  __syncthreads();   // constants + pulses visible

  // H(0) = herm(H0) + sum_c u_c herm(Hc)
  {
    float u0 = sU[0][0], u1 = sU[0][1], u2 = sU[0][2], u3 = sU[0][3];
    sHr[i*SS+j] = sH0r[i*SS+j] + u0*sHcr[0][i*SS+j] + u1*sHcr[1][i*SS+j]
                               + u2*sHcr[2][i*SS+j] + u3*sHcr[3][i*SS+j];
    sHi[i*SS+j] = sH0i[i*SS+j] + u0*sHci[0][i*SS+j] + u1*sHci[1][i*SS+j]
                               + u2*sHci[2][i*SS+j] + u3*sHci[3][i*SS+j];
  }

  // ---- main Euler loop: drho = -i(H rho - rho H) + sum_k L_k rho L_k^dag - 0.5(LdL rho + rho LdL) ----
  #pragma unroll 1
  for (int t = 0; t < NTS; ++t) {
    __syncthreads();   // barrier A: H(t), rho(t) visible

    float c1r=0.f,c1i=0.f, c2r=0.f,c2i=0.f, d1r=0.f,d1i=0.f, d2r=0.f,d2i=0.f;
    #pragma unroll
    for (int m = 0; m < DIM; ++m) {
      float h_im_r = sHr[i*SS+m], h_im_i = sHi[i*SS+m];   // H[i][m]
      float h_mj_r = sHr[m*SS+j], h_mj_i = sHi[m*SS+j];   // H[m][j]
      float r_mj_r = sRr[m*SS+j], r_mj_i = sRi[m*SS+j];   // rho[m][j]
      float r_im_r = sRr[i*SS+m], r_im_i = sRi[i*SS+m];   // rho[i][m]
      float d_im_r = sDr[i*SS+m], d_im_i = sDi[i*SS+m];   // LdL[i][m]
      float d_mj_r = sDr[m*SS+j], d_mj_i = sDi[m*SS+j];   // LdL[m][j]
      c1r += h_im_r*r_mj_r - h_im_i*r_mj_i;  c1i += h_im_r*r_mj_i + h_im_i*r_mj_r;  // (H rho)[i][j]
      c2r += r_im_r*h_mj_r - r_im_i*h_mj_i;  c2i += r_im_r*h_mj_i + r_im_i*h_mj_r;  // (rho H)[i][j]
      d1r += d_im_r*r_mj_r - d_im_i*r_mj_i;  d1i += d_im_r*r_mj_i + d_im_i*r_mj_r;  // (LdL rho)[i][j]
      d2r += r_im_r*d_mj_r - r_im_i*d_mj_i;  d2i += r_im_r*d_mj_i + r_im_i*d_mj_r;  // (rho LdL)[i][j]
    }
    // T_k = L_k rho
    #pragma unroll
    for (int k = 0; k < KL; ++k) {
      float tr_ = 0.f, ti_ = 0.f;
      #pragma unroll
      for (int m = 0; m < DIM; ++m) {
        float l_r = sLr[k][i*SS+m], l_i = sLi[k][i*SS+m];  // L_k[i][m]
        float r_r = sRr[m*SS+j],    r_i = sRi[m*SS+j];     // rho[m][j]
        tr_ += l_r*r_r - l_i*r_i;
        ti_ += l_r*r_i + l_i*r_r;
      }
      sTr[k][i*SS+j] = tr_;
      sTi[k][i*SS+j] = ti_;
    }

    __syncthreads();   // barrier B: T visible

    // jump[i][j] = sum_k sum_m T_k[i][m] * conj(L_k[j][m])
    float jr = 0.f, jiv = 0.f;
    #pragma unroll
    for (int k = 0; k < KL; ++k) {
      #pragma unroll
      for (int m = 0; m < DIM; ++m) {
        float t_r = sTr[k][i*SS+m], t_i = sTi[k][i*SS+m];
        float l_r = sLr[k][j*SS+m], l_i = sLi[k][j*SS+m];
        jr  += t_r*l_r + t_i*l_i;
        jiv += t_i*l_r - t_r*l_i;
      }
    }

    // -i*(C1 - C2): re = (c1i - c2i), im = -(c1r - c2r)
    float dr = (c1i - c2i) + jr  - 0.5f*(d1r + d2r);
    float di = (c2r - c1r) + jiv - 0.5f*(d1i + d2i);
    rr += DTF * dr;
    ri += DTF * di;

    if (i == j) g_out[(t*BATCH + b)*DIM + i] = rr;   // f32 store

    // publish rho(t+1) and H(t+1); visible after next barrier A
    sRr[i*SS + j] = rr;
    sRi[i*SS + j] = ri;
    if (t + 1 < NTS) {
      float u0 = sU[t+1][0], u1 = sU[t+1][1], u2 = sU[t+1][2], u3 = sU[t+1][3];
      sHr[i*SS+j] = sH0r[i*SS+j] + u0*sHcr[0][i*SS+j] + u1*sHcr[1][i*SS+j]
                                 + u2*sHcr[2][i*SS+j] + u3*sHcr[3][i*SS+j];
      sHi[i*SS+j] = sH0i[i*SS+j] + u0*sHci[0][i*SS+j] + u1*sHci[1][i*SS+j]
                                 + u2*sHci[2][i*SS+j] + u3*sHci[3][i*SS+j];
    }
  }
}

extern "C" void kernel_launch(void* const* d_in, const int* in_sizes, int n_in,
                              void* d_out, int out_size, void* d_ws, size_t ws_size,
                              hipStream_t stream) {
  (void)out_size; (void)d_ws; (void)ws_size;
  // Resolve input ordering from in_sizes. Documented order (setup_inputs dict):
  //   params(64), H0_re(256), H0_im(256), Hc_re(1024), Hc_im(1024),
  //   L_re(1024), L_im(1024), rho0_re(8192), rho0_im(8192)
  // Defensive: if the unique size-64 entry (params) is at index 6, the order is
  // alphabetical (H0_im,H0_re,Hc_im,Hc_re,L_im,L_re,params,rho0_im,rho0_re).
  const void *P, *H0r, *H0i, *Hcr, *Hci, *Lr, *Li, *R0r, *R0i;
  int idx64 = -1;
  for (int q = 0; q < n_in; ++q) if (in_sizes[q] == 64) idx64 = q;
  if (idx64 == 6) {
    H0i = d_in[0]; H0r = d_in[1];
    Hci = d_in[2]; Hcr = d_in[3];
    Li  = d_in[4]; Lr  = d_in[5];
    P   = d_in[6];
    R0i = d_in[7]; R0r = d_in[8];
  } else {
    P   = d_in[0];
    H0r = d_in[1]; H0i = d_in[2];
    Hcr = d_in[3]; Hci = d_in[4];
    Lr  = d_in[5]; Li  = d_in[6];
    R0r = d_in[7]; R0i = d_in[8];
  }
  lindblad_evolve<<<dim3(BATCH), dim3(256), 0, stream>>>(
      P, H0r, H0i, Hcr, Hci, Lr, Li, R0r, R0i, (float*)d_out);
}

// Round 6
// 1582.554 us; speedup vs baseline: 1.7341x; 1.7341x over previous
//
#include <hip/hip_runtime.h>
#include <hip/hip_bf16.h>

// Problem constants
#define DIM    16
#define BATCH  32
#define KL     4          // Lindblad operators
#define NTS    512        // Euler steps
#define NC     4          // control channels
#define NPAR   16         // spline params per channel
#define SS     20         // LDS row stride in f32 units: 80 B, 16B-aligned, <=2-way banks
#define DTF    (1.0f/512.0f)

__device__ __forceinline__ float b2f(__hip_bfloat16 x) { return __bfloat162float(x); }

// dtype-agnostic scalar load for setup (inputs f32 on this dataset; detector keeps it robust)
__device__ __forceinline__ float ldval(const void* p, int idx, bool isf32) {
  return isf32 ? ((const float*)p)[idx]
               : __bfloat162float(((const __hip_bfloat16*)p)[idx]);
}

// f32 complex row load: 4+4 ds_read_b128
#define LOADROW(dstr_, dsti_, srcr_, srci_, row_)                          \
  {                                                                        \
    _Pragma("unroll")                                                      \
    for (int q_ = 0; q_ < 4; ++q_) {                                       \
      float4 vr_ = *(const float4*)&(srcr_)[(row_)*SS + 4*q_];             \
      float4 vi_ = *(const float4*)&(srci_)[(row_)*SS + 4*q_];             \
      (dstr_)[4*q_+0] = vr_.x; (dstr_)[4*q_+1] = vr_.y;                    \
      (dstr_)[4*q_+2] = vr_.z; (dstr_)[4*q_+3] = vr_.w;                    \
      (dsti_)[4*q_+0] = vi_.x; (dsti_)[4*q_+1] = vi_.y;                    \
      (dsti_)[4*q_+2] = vi_.z; (dsti_)[4*q_+3] = vi_.w;                    \
    }                                                                      \
  }

__global__ __launch_bounds__(256, 1)
void lindblad_evolve(const void* __restrict__ g_params,
                     const void* __restrict__ g_H0re, const void* __restrict__ g_H0im,
                     const void* __restrict__ g_Hcre, const void* __restrict__ g_Hcim,
                     const void* __restrict__ g_Lre,  const void* __restrict__ g_Lim,
                     const void* __restrict__ g_r0re, const void* __restrict__ g_r0im,
                     float* __restrict__ g_out)
{
  __shared__ float sU[NTS][NC];                              // control pulses
  __shared__ __align__(16) float sGr[DIM*SS], sGi[DIM*SS];   // G(t) = G0 + sum u_c Gc
  __shared__ __align__(16) float sCr[DIM*SS], sCi[DIM*SS];   // rho^T: sC[j][i] = rho[i][j]
  __shared__ __align__(16) float sMr[DIM*SS], sMi[DIM*SS];   // M = G*rho
  __shared__ __align__(16) float sLr[KL][DIM*SS], sLi[KL][DIM*SS]; // L_k (setup only)
  __shared__ __align__(16) float sTr[KL][DIM*SS], sTi[KL][DIM*SS]; // T_k = L_k*rho
  __shared__ int sFlag;

  const int tid = threadIdx.x;
  const int b   = blockIdx.x;
  const int i   = tid >> 4;
  const int j   = tid & 15;

  // ---- input storage-dtype detection ----
  if (tid == 0) sFlag = 0;
  __syncthreads();
  {
    float v = b2f(((const __hip_bfloat16*)g_H0re)[tid]);
    if (!(fabsf(v) <= 1e10f)) atomicOr(&sFlag, 1);
  }
  __syncthreads();
  const bool isf32 = (sFlag != 0);

  // ---- B-spline control pulses ----
  {
    float kn[20];
    kn[0] = 0.f; kn[1] = 0.f; kn[2] = 0.f;
    #pragma unroll
    for (int q = 0; q < 14; ++q) kn[3 + q] = (float)q / 13.0f;
    kn[17] = 1.f; kn[18] = 1.f; kn[19] = 1.f;
    #pragma unroll
    for (int rep = 0; rep < 2; ++rep) {
      const int ts = tid + rep * 256;
      const float t = (float)ts * DTF;
      float B[19];
      #pragma unroll
      for (int q = 0; q < 19; ++q) B[q] = (kn[q] <= t && t < kn[q+1]) ? 1.f : 0.f;
      #pragma unroll
      for (int d = 1; d <= 3; ++d) {
        #pragma unroll
        for (int q = 0; q + d < 19; ++q) {
          float ld = kn[q+d]   - kn[q];
          float rd = kn[q+d+1] - kn[q+1];
          float lv = (ld > 0.f) ? (t - kn[q])     / ld * B[q]   : 0.f;
          float rv = (rd > 0.f) ? (kn[q+d+1] - t) / rd * B[q+1] : 0.f;
          B[q] = lv + rv;
        }
      }
      #pragma unroll
      for (int c = 0; c < NC; ++c) {
        float s = 0.f;
        #pragma unroll
        for (int q = 0; q < NPAR; ++q) s += B[q] * ldval(g_params, q*NC + c, isf32);
        sU[ts][c] = s;
      }
    }
  }

  // ---- constants: G0 = -i*herm(H0) - 0.5*LdL (own element, regs), Gc (regs), L (LDS) ----
  float g0r, g0i, gcr[NC], gci[NC];
  {
    const int ij = i*16 + j, ji = j*16 + i;
    float h0r = 0.5f * (ldval(g_H0re, ij, isf32) + ldval(g_H0re, ji, isf32));
    float h0i = 0.5f * (ldval(g_H0im, ij, isf32) - ldval(g_H0im, ji, isf32));
    float ldr = 0.f, ldi = 0.f;   // LdL[i][j] = sum_{k,m} conj(L[k][m][i]) L[k][m][j]
    for (int k = 0; k < KL; ++k) {
      #pragma unroll
      for (int m = 0; m < DIM; ++m) {
        float ar = ldval(g_Lre, k*256 + m*16 + i, isf32), ai = ldval(g_Lim, k*256 + m*16 + i, isf32);
        float br = ldval(g_Lre, k*256 + m*16 + j, isf32), bi = ldval(g_Lim, k*256 + m*16 + j, isf32);
        ldr += ar*br + ai*bi;
        ldi += ar*bi - ai*br;
      }
    }
    g0r =  h0i - 0.5f*ldr;
    g0i = -h0r - 0.5f*ldi;
    #pragma unroll
    for (int c = 0; c < NC; ++c) {
      float hr = 0.5f * (ldval(g_Hcre, c*256 + ij, isf32) + ldval(g_Hcre, c*256 + ji, isf32));
      float hi = 0.5f * (ldval(g_Hcim, c*256 + ij, isf32) - ldval(g_Hcim, c*256 + ji, isf32));
      gcr[c] =  hi;          // -i * herm(Hc)
      gci[c] = -hr;
    }
    #pragma unroll
    for (int k = 0; k < KL; ++k) {
      sLr[k][i*SS + j] = ldval(g_Lre, k*256 + ij, isf32);
      sLi[k][i*SS + j] = ldval(g_Lim, k*256 + ij, isf32);
    }
  }
  float rr = ldval(g_r0re, b*256 + i*16 + j, isf32);   // own rho element (f32 master)
  float ri = ldval(g_r0im, b*256 + i*16 + j, isf32);
  sCr[j*SS + i] = rr;    // transpose-only storage: col j of rho == row j of sC
  sCi[j*SS + i] = ri;

  __syncthreads();       // sU, sL, sC visible

  // ---- preload constant L rows into registers: row i (for T) and row j (for J) ----
  float Lir[KL][16], Lii[KL][16], Ljr[KL][16], Lji[KL][16];
  #pragma unroll
  for (int k = 0; k < KL; ++k) {
    LOADROW((&Lir[k][0]), (&Lii[k][0]), sLr[k], sLi[k], i);
    LOADROW((&Ljr[k][0]), (&Lji[k][0]), sLr[k], sLi[k], j);
  }

  // G(0)
  {
    float u0 = sU[0][0], u1 = sU[0][1], u2 = sU[0][2], u3 = sU[0][3];
    sGr[i*SS+j] = g0r + u0*gcr[0] + u1*gcr[1] + u2*gcr[2] + u3*gcr[3];
    sGi[i*SS+j] = g0i + u0*gci[0] + u1*gci[1] + u2*gci[2] + u3*gci[3];
  }

  // ---- main Euler loop ----
  // drho = M + conj(M^T) + J, where M = G*rho (rho stays Hermitian under this update)
  #pragma unroll 1
  for (int t = 0; t < NTS; ++t) {
    __syncthreads();   // barrier A: G(t), rho^T(t) visible

    float cr[16], ci[16];            // col j of rho
    LOADROW(cr, ci, sCr, sCi, j);

    // M[i][j] = (G rho)[i][j]
    float mr = 0.f, mi = 0.f;
    {
      float gr[16], gi[16];
      LOADROW(gr, gi, sGr, sGi, i);
      #pragma unroll
      for (int m = 0; m < 16; ++m) {
        mr += gr[m]*cr[m] - gi[m]*ci[m];
        mi += gr[m]*ci[m] + gi[m]*cr[m];
      }
    }
    sMr[i*SS + j] = mr;
    sMi[i*SS + j] = mi;

    // T_k = L_k * rho  (L row i from registers)
    #pragma unroll
    for (int k = 0; k < KL; ++k) {
      float tr_ = 0.f, ti_ = 0.f;
      #pragma unroll
      for (int m = 0; m < 16; ++m) {
        tr_ += Lir[k][m]*cr[m] - Lii[k][m]*ci[m];
        ti_ += Lir[k][m]*ci[m] + Lii[k][m]*cr[m];
      }
      sTr[k][i*SS + j] = tr_;
      sTi[k][i*SS + j] = ti_;
    }

    __syncthreads();   // barrier B: M, T visible

    // N = conj(M[j][i]) ; J[i][j] = sum_k sum_m T_k[i][m] conj(L_k[j][m])
    float nr =  sMr[j*SS + i];
    float ni = -sMi[j*SS + i];
    float dr = 0.f, di = 0.f;
    #pragma unroll
    for (int k = 0; k < KL; ++k) {
      float tr[16], ti[16];
      LOADROW(tr, ti, sTr[k], sTi[k], i);
      #pragma unroll
      for (int m = 0; m < 16; ++m) {
        dr += tr[m]*Ljr[k][m] + ti[m]*Lji[k][m];    // t * conj(l)
        di += ti[m]*Ljr[k][m] - tr[m]*Lji[k][m];
      }
    }
    dr += mr + nr;
    di += mi + ni;
    rr += DTF * dr;
    ri += DTF * di;

    if (i == j) g_out[(t*BATCH + b)*DIM + i] = rr;

    // publish rho^T(t+1) and G(t+1); consumed after next barrier A.
    sCr[j*SS + i] = rr;
    sCi[j*SS + i] = ri;
    if (t + 1 < NTS) {
      float u0 = sU[t+1][0], u1 = sU[t+1][1], u2 = sU[t+1][2], u3 = sU[t+1][3];
      sGr[i*SS+j] = g0r + u0*gcr[0] + u1*gcr[1] + u2*gcr[2] + u3*gcr[3];
      sGi[i*SS+j] = g0i + u0*gci[0] + u1*gci[1] + u2*gci[2] + u3*gci[3];
    }
  }
}

extern "C" void kernel_launch(void* const* d_in, const int* in_sizes, int n_in,
                              void* d_out, int out_size, void* d_ws, size_t ws_size,
                              hipStream_t stream) {
  (void)out_size; (void)d_ws; (void)ws_size;
  // Input-order hedge (R4-verified: documented dict order, else-branch)
  const void *P, *H0r, *H0i, *Hcr, *Hci, *Lr, *Li, *R0r, *R0i;
  int idx64 = -1;
  for (int q = 0; q < n_in; ++q) if (in_sizes[q] == 64) idx64 = q;
  if (idx64 == 6) {   // alphabetical fallback
    H0i = d_in[0]; H0r = d_in[1];
    Hci = d_in[2]; Hcr = d_in[3];
    Li  = d_in[4]; Lr  = d_in[5];
    P   = d_in[6];
    R0i = d_in[7]; R0r = d_in[8];
  } else {            // documented setup_inputs() dict order
    P   = d_in[0];
    H0r = d_in[1]; H0i = d_in[2];
    Hcr = d_in[3]; Hci = d_in[4];
    Lr  = d_in[5]; Li  = d_in[6];
    R0r = d_in[7]; R0i = d_in[8];
  }
  lindblad_evolve<<<dim3(BATCH), dim3(256), 0, stream>>>(
      P, H0r, H0i, Hcr, Hci, Lr, Li, R0r, R0i, (float*)d_out);
}

// Round 7
// 615.692 us; speedup vs baseline: 4.4573x; 2.5704x over previous
//
#include <hip/hip_runtime.h>
#include <hip/hip_bf16.h>

// Problem constants
#define DIM    16
#define BATCH  32
#define KL     4          // Lindblad operators
#define NTS    512        // Euler steps
#define NC     4          // control channels
#define NPAR   16         // spline params per channel
#define DTF    (1.0f/512.0f)
// bf16 A/B operand arrays: 16 rows x 32 cols, row stride 40 ushort (80 B):
//  - 16B-aligned fragment loads (ds_read_b128)
//  - banks: (m*20 + 4q) % 32 -> only (m, m+8) alias = 2-way = free (m136)
#define BST    40
// f32 tile arrays stride 20 (m137-style padding)
#define FST    20

using short8 = __attribute__((ext_vector_type(8))) short;   // 8 bf16 (guide-verified type)
using f32x4  = __attribute__((ext_vector_type(4))) float;

__device__ __forceinline__ float b2f(__hip_bfloat16 x) { return __bfloat162float(x); }

__device__ __forceinline__ float ldval(const void* p, int idx, bool isf32) {
  return isf32 ? ((const float*)p)[idx]
               : __bfloat162float(((const __hip_bfloat16*)p)[idx]);
}

// f32 -> bf16 (RNE) and back, on raw ushort
__device__ __forceinline__ unsigned short f2bf(float x) {
  unsigned u = __float_as_uint(x);
  unsigned r = u + 0x7FFFu + ((u >> 16) & 1u);
  return (unsigned short)(r >> 16);
}
__device__ __forceinline__ float bf2f(unsigned short h) {
  return __uint_as_float(((unsigned)h) << 16);
}

__device__ __forceinline__ short8 ldfrag(const unsigned short* p) {
  return *(const short8*)p;
}
__device__ __forceinline__ short8 negbf8(short8 a) {   // negate 8 bf16 (sign-bit XOR)
  union { short8 s; unsigned u[4]; } v; v.s = a;
  #pragma unroll
  for (int q = 0; q < 4; ++q) v.u[q] ^= 0x80008000u;
  return v.s;
}

// 3-term split-precision MFMA: C += (Ah+Al)*(Bh+Bl), dropping Al*Bl (~2^-18)
__device__ __forceinline__ f32x4 mm3(short8 Ah, short8 Al, short8 Bh, short8 Bl, f32x4 acc) {
  acc = __builtin_amdgcn_mfma_f32_16x16x32_bf16(Ah, Bh, acc, 0, 0, 0);
  acc = __builtin_amdgcn_mfma_f32_16x16x32_bf16(Al, Bh, acc, 0, 0, 0);
  acc = __builtin_amdgcn_mfma_f32_16x16x32_bf16(Ah, Bl, acc, 0, 0, 0);
  return acc;
}

__global__ __launch_bounds__(256, 1)
void lindblad_evolve(const void* __restrict__ g_params,
                     const void* __restrict__ g_H0re, const void* __restrict__ g_H0im,
                     const void* __restrict__ g_Hcre, const void* __restrict__ g_Hcim,
                     const void* __restrict__ g_Lre,  const void* __restrict__ g_Lim,
                     const void* __restrict__ g_r0re, const void* __restrict__ g_r0im,
                     float* __restrict__ g_out)
{
  // bf16 operand stores (hi/lo split), A-layout row-major [row][k0..31], k<16 = re, k>=16 = im
  __shared__ __align__(16) unsigned short sGh[16*BST], sGl[16*BST];       // G' = [Gr|Gi]
  __shared__ __align__(16) unsigned short sPh[16*BST], sPl[16*BST];       // rho^T' = [rho_r^T|rho_i^T]
  __shared__ __align__(16) unsigned short sTh[KL][16*BST], sTl[KL][16*BST]; // T'_k = [Tr|Ti]
  __shared__ __align__(16) unsigned short sLh[KL][16*BST], sLl[KL][16*BST]; // L'_k = [Lr|Li]
  // f32 tile outputs
  __shared__ __align__(16) float sMr[16*FST], sMi[16*FST], sJr[16*FST], sJi[16*FST];
  __shared__ float sU[NTS][NC];
  __shared__ int sFlag;

  const int tid = threadIdx.x;
  const int b   = blockIdx.x;
  const int i   = tid >> 4;       // elementwise: own rho element (i,j)
  const int j   = tid & 15;
  const int wv  = tid >> 6;       // wave id 0..3
  const int ln  = tid & 63;
  const int fm  = ln & 15;        // fragment non-K index (A: row m; B: col n)
  const int fq  = ln >> 4;        // k-octet 0..3
  const int row0 = fq * 4;        // C-layout: row = fq*4 + reg, col = fm (m89-verified)
  const int fOff  = fm*BST + fq*8;                 // straight fragment offset
  const int fOffS = fm*BST + ((fq*8 + 16) & 31);   // half-swapped offset

  // ---- input storage-dtype detection (R1/R2-verified: this dataset is f32) ----
  if (tid == 0) sFlag = 0;
  __syncthreads();
  {
    float v = b2f(((const __hip_bfloat16*)g_H0re)[tid]);
    if (!(fabsf(v) <= 1e10f)) atomicOr(&sFlag, 1);
  }
  __syncthreads();
  const bool isf32 = (sFlag != 0);

  // ---- B-spline control pulses (verified R4) ----
  {
    float kn[20];
    kn[0] = 0.f; kn[1] = 0.f; kn[2] = 0.f;
    #pragma unroll
    for (int q = 0; q < 14; ++q) kn[3 + q] = (float)q / 13.0f;
    kn[17] = 1.f; kn[18] = 1.f; kn[19] = 1.f;
    #pragma unroll
    for (int rep = 0; rep < 2; ++rep) {
      const int ts = tid + rep * 256;
      const float t = (float)ts * DTF;
      float B[19];
      #pragma unroll
      for (int q = 0; q < 19; ++q) B[q] = (kn[q] <= t && t < kn[q+1]) ? 1.f : 0.f;
      #pragma unroll
      for (int d = 1; d <= 3; ++d) {
        #pragma unroll
        for (int q = 0; q + d < 19; ++q) {
          float ld = kn[q+d]   - kn[q];
          float rd = kn[q+d+1] - kn[q+1];
          float lv = (ld > 0.f) ? (t - kn[q])     / ld * B[q]   : 0.f;
          float rv = (rd > 0.f) ? (kn[q+d+1] - t) / rd * B[q+1] : 0.f;
          B[q] = lv + rv;
        }
      }
      #pragma unroll
      for (int c = 0; c < NC; ++c) {
        float s = 0.f;
        #pragma unroll
        for (int q = 0; q < NPAR; ++q) s += B[q] * ldval(g_params, q*NC + c, isf32);
        sU[ts][c] = s;
      }
    }
  }

  // ---- constants: G0 = -i*herm(H0) - 0.5*LdL (regs), Gc (regs), L' staged hi/lo ----
  float g0r, g0i, gcr[NC], gci[NC];
  {
    const int ij = i*16 + j, ji = j*16 + i;
    float h0r = 0.5f * (ldval(g_H0re, ij, isf32) + ldval(g_H0re, ji, isf32));
    float h0i = 0.5f * (ldval(g_H0im, ij, isf32) - ldval(g_H0im, ji, isf32));
    float ldr = 0.f, ldi = 0.f;
    for (int k = 0; k < KL; ++k) {
      #pragma unroll
      for (int m = 0; m < DIM; ++m) {
        float ar = ldval(g_Lre, k*256 + m*16 + i, isf32), ai = ldval(g_Lim, k*256 + m*16 + i, isf32);
        float br = ldval(g_Lre, k*256 + m*16 + j, isf32), bi = ldval(g_Lim, k*256 + m*16 + j, isf32);
        ldr += ar*br + ai*bi;
        ldi += ar*bi - ai*br;
      }
    }
    g0r =  h0i - 0.5f*ldr;
    g0i = -h0r - 0.5f*ldi;
    #pragma unroll
    for (int c = 0; c < NC; ++c) {
      float hr = 0.5f * (ldval(g_Hcre, c*256 + ij, isf32) + ldval(g_Hcre, c*256 + ji, isf32));
      float hi = 0.5f * (ldval(g_Hcim, c*256 + ij, isf32) - ldval(g_Hcim, c*256 + ji, isf32));
      gcr[c] =  hi;
      gci[c] = -hr;
    }
    // stage L'_k = [Lr|Li] hi/lo: thread (i,j) writes row i, cols j and 16+j
    #pragma unroll
    for (int k = 0; k < KL; ++k) {
      float lr = ldval(g_Lre, k*256 + ij, isf32);
      float li = ldval(g_Lim, k*256 + ij, isf32);
      unsigned short h;
      h = f2bf(lr); sLh[k][i*BST + j]      = h; sLl[k][i*BST + j]      = f2bf(lr - bf2f(h));
      h = f2bf(li); sLh[k][i*BST + 16 + j] = h; sLl[k][i*BST + 16 + j] = f2bf(li - bf2f(h));
    }
  }
  float rr = ldval(g_r0re, b*256 + i*16 + j, isf32);   // f32 master rho element
  float ri = ldval(g_r0im, b*256 + i*16 + j, isf32);

  __syncthreads();   // sU, sL staged

  // ---- preload loop-constant fragments into registers ----
  short8 A0h, A0l, A1h, A1l;        // phase-1 A operands (wave-specific L'_k)
  short8 JBh[KL], JBl[KL];          // phase-2 B operands (w0: Jr-type, w1: Ji-type)
  if (wv == 0) {
    A0h = ldfrag(&sLh[0][fOff]); A0l = ldfrag(&sLl[0][fOff]);   // for T0r
    #pragma unroll
    for (int k = 0; k < KL; ++k) {      // Jr B = straight L' (B[k][n] ok: (L†)r^T=Lr, -(L†)i^T=Li)
      JBh[k] = ldfrag(&sLh[k][fOff]);
      JBl[k] = ldfrag(&sLl[k][fOff]);
    }
  } else if (wv == 1) {
    A0h = ldfrag(&sLh[0][fOff]); A0l = ldfrag(&sLl[0][fOff]);   // T0i
    A1h = ldfrag(&sLh[1][fOff]); A1l = ldfrag(&sLl[1][fOff]);   // T1r/T1i
    #pragma unroll
    for (int k = 0; k < KL; ++k) {      // Ji B = [-Li | Lr]: swapped halves, negate k<16 (fq<2)
      short8 h = ldfrag(&sLh[k][fOffS]);
      short8 l = ldfrag(&sLl[k][fOffS]);
      if (fq < 2) { h = negbf8(h); l = negbf8(l); }
      JBh[k] = h; JBl[k] = l;
    }
  } else if (wv == 2) {
    A0h = ldfrag(&sLh[2][fOff]); A0l = ldfrag(&sLl[2][fOff]);
  } else {
    A0h = ldfrag(&sLh[3][fOff]); A0l = ldfrag(&sLl[3][fOff]);
  }

  // ---- publish rho^T'(0) and G'(0) ----
  {
    unsigned short h;
    h = f2bf(rr); sPh[j*BST + i]      = h; sPl[j*BST + i]      = f2bf(rr - bf2f(h));
    h = f2bf(ri); sPh[j*BST + 16 + i] = h; sPl[j*BST + 16 + i] = f2bf(ri - bf2f(h));
    float u0 = sU[0][0], u1 = sU[0][1], u2 = sU[0][2], u3 = sU[0][3];
    float gr = g0r + u0*gcr[0] + u1*gcr[1] + u2*gcr[2] + u3*gcr[3];
    float gi = g0i + u0*gci[0] + u1*gci[1] + u2*gci[2] + u3*gci[3];
    h = f2bf(gr); sGh[i*BST + j]      = h; sGl[i*BST + j]      = f2bf(gr - bf2f(h));
    h = f2bf(gi); sGh[i*BST + 16 + j] = h; sGl[i*BST + 16 + j] = f2bf(gi - bf2f(h));
  }

  #define WRITE_TILE_F32(dst, acc)                                   \
    { _Pragma("unroll") for (int r_ = 0; r_ < 4; ++r_)               \
        (dst)[(row0 + r_)*FST + fm] = (acc)[r_]; }
  #define WRITE_TILE_BF(dh, dl, acc, co)                             \
    { _Pragma("unroll") for (int r_ = 0; r_ < 4; ++r_) {             \
        float v_ = (acc)[r_];                                        \
        unsigned short h_ = f2bf(v_);                                \
        (dh)[(row0 + r_)*BST + (co) + fm] = h_;                      \
        (dl)[(row0 + r_)*BST + (co) + fm] = f2bf(v_ - bf2f(h_)); } }

  // ---- main Euler loop ----
  #pragma unroll 1
  for (int t = 0; t < NTS; ++t) {
    __syncthreads();   // B1: rho^T'(t), G'(t) visible

    // ---- phase 1: M = G*rho, T_k = L_k*rho ----
    {
      // B fragments from rho^T' = [rr^T | ri^T]:
      //  r-type (Cr): [rho_r; -rho_i] -> straight load, negate k>=16 (fq>=2)
      //  i-type (Ci): [rho_i;  rho_r] -> half-swapped load, no negation
      short8 Brh = ldfrag(&sPh[fOff]),  Brl = ldfrag(&sPl[fOff]);
      if (fq >= 2) { Brh = negbf8(Brh); Brl = negbf8(Brl); }
      short8 Bih = ldfrag(&sPh[fOffS]), Bil = ldfrag(&sPl[fOffS]);

      if (wv == 0) {
        short8 Gh = ldfrag(&sGh[fOff]), Gl = ldfrag(&sGl[fOff]);
        f32x4 aMr = {0.f,0.f,0.f,0.f}, aMi = {0.f,0.f,0.f,0.f}, aT = {0.f,0.f,0.f,0.f};
        aMr = mm3(Gh, Gl, Brh, Brl, aMr);
        aMi = mm3(Gh, Gl, Bih, Bil, aMi);
        aT  = mm3(A0h, A0l, Brh, Brl, aT);           // T0r
        WRITE_TILE_F32(sMr, aMr);
        WRITE_TILE_F32(sMi, aMi);
        WRITE_TILE_BF(sTh[0], sTl[0], aT, 0);
      } else if (wv == 1) {
        f32x4 a0 = {0.f,0.f,0.f,0.f}, a1 = {0.f,0.f,0.f,0.f}, a2 = {0.f,0.f,0.f,0.f};
        a0 = mm3(A0h, A0l, Bih, Bil, a0);            // T0i
        a1 = mm3(A1h, A1l, Brh, Brl, a1);            // T1r
        a2 = mm3(A1h, A1l, Bih, Bil, a2);            // T1i
        WRITE_TILE_BF(sTh[0], sTl[0], a0, 16);
        WRITE_TILE_BF(sTh[1], sTl[1], a1, 0);
        WRITE_TILE_BF(sTh[1], sTl[1], a2, 16);
      } else if (wv == 2) {
        f32x4 a1 = {0.f,0.f,0.f,0.f}, a2 = {0.f,0.f,0.f,0.f};
        a1 = mm3(A0h, A0l, Brh, Brl, a1);            // T2r
        a2 = mm3(A0h, A0l, Bih, Bil, a2);            // T2i
        WRITE_TILE_BF(sTh[2], sTl[2], a1, 0);
        WRITE_TILE_BF(sTh[2], sTl[2], a2, 16);
      } else {
        f32x4 a1 = {0.f,0.f,0.f,0.f}, a2 = {0.f,0.f,0.f,0.f};
        a1 = mm3(A0h, A0l, Brh, Brl, a1);            // T3r
        a2 = mm3(A0h, A0l, Bih, Bil, a2);            // T3i
        WRITE_TILE_BF(sTh[3], sTl[3], a1, 0);
        WRITE_TILE_BF(sTh[3], sTl[3], a2, 16);
      }
    }

    __syncthreads();   // B2: T', M visible

    // ---- phase 2: J = sum_k T_k * L_k^dag (w0: Jr, w1: Ji) ----
    if (wv < 2) {
      f32x4 a = {0.f,0.f,0.f,0.f};
      #pragma unroll
      for (int k = 0; k < KL; ++k) {
        short8 Th = ldfrag(&sTh[k][fOff]);
        short8 Tl = ldfrag(&sTl[k][fOff]);
        a = mm3(Th, Tl, JBh[k], JBl[k], a);
      }
      if (wv == 0) { WRITE_TILE_F32(sJr, a); }
      else         { WRITE_TILE_F32(sJi, a); }
    }

    __syncthreads();   // B3: J visible

    // ---- elementwise: drho = M + conj(M^T) + J; Euler update; republish ----
    {
      float mr  = sMr[i*FST + j], mi_ = sMi[i*FST + j];
      float mrt = sMr[j*FST + i], mit = sMi[j*FST + i];
      float jr  = sJr[i*FST + j], jiv = sJi[i*FST + j];
      rr += DTF * (mr + mrt + jr);
      ri += DTF * (mi_ - mit + jiv);

      if (i == j) g_out[(t*BATCH + b)*DIM + i] = rr;

      unsigned short h;
      h = f2bf(rr); sPh[j*BST + i]      = h; sPl[j*BST + i]      = f2bf(rr - bf2f(h));
      h = f2bf(ri); sPh[j*BST + 16 + i] = h; sPl[j*BST + 16 + i] = f2bf(ri - bf2f(h));

      const int tn = (t + 1 < NTS) ? (t + 1) : t;
      float u0 = sU[tn][0], u1 = sU[tn][1], u2 = sU[tn][2], u3 = sU[tn][3];
      float gr = g0r + u0*gcr[0] + u1*gcr[1] + u2*gcr[2] + u3*gcr[3];
      float gi = g0i + u0*gci[0] + u1*gci[1] + u2*gci[2] + u3*gci[3];
      h = f2bf(gr); sGh[i*BST + j]      = h; sGl[i*BST + j]      = f2bf(gr - bf2f(h));
      h = f2bf(gi); sGh[i*BST + 16 + j] = h; sGl[i*BST + 16 + j] = f2bf(gi - bf2f(h));
    }
  }
}

extern "C" void kernel_launch(void* const* d_in, const int* in_sizes, int n_in,
                              void* d_out, int out_size, void* d_ws, size_t ws_size,
                              hipStream_t stream) {
  (void)out_size; (void)d_ws; (void)ws_size;
  const void *P, *H0r, *H0i, *Hcr, *Hci, *Lr, *Li, *R0r, *R0i;
  int idx64 = -1;
  for (int q = 0; q < n_in; ++q) if (in_sizes[q] == 64) idx64 = q;
  if (idx64 == 6) {   // alphabetical fallback
    H0i = d_in[0]; H0r = d_in[1];
    Hci = d_in[2]; Hcr = d_in[3];
    Li  = d_in[4]; Lr  = d_in[5];
    P   = d_in[6];
    R0i = d_in[7]; R0r = d_in[8];
  } else {            // documented setup_inputs() dict order (R4-verified)
    P   = d_in[0];
    H0r = d_in[1]; H0i = d_in[2];
    Hcr = d_in[3]; Hci = d_in[4];
    Lr  = d_in[5]; Li  = d_in[6];
    R0r = d_in[7]; R0i = d_in[8];
  }
  lindblad_evolve<<<dim3(BATCH), dim3(256), 0, stream>>>(
      P, H0r, H0i, Hcr, Hci, Lr, Li, R0r, R0i, (float*)d_out);
}